// Round 8
// baseline (238.015 us; speedup 1.0000x reference)
//
#include <hip/hip_runtime.h>

constexpr int Tt = 384;   // timesteps
constexpr int Cc = 96;    // classes (blank = 95)
constexpr int Ll = 48;    // max label length
constexpr int Gg = 8;     // rows per group (= rescale period)
constexpr int NG = 24;    // groups per direction (24*8 = 192)
constexpr int RSo = 50;   // LDS row stride: pl lanes 0..48, pb at 49
constexpr int SLOT = Gg * RSo;   // 400 floats per group slot
constexpr int RING = 12;  // ring slots per direction (2*12*400*4 = 38.4 KB)

#define L2E 1.4426950408889634f
#define LN2 0.6931471805599453f
#define LNEG (-3.0e38f)

// ---- DPP helpers (VALU pipe) ----
template <int CTRL, int RM = 0xF>
__device__ __forceinline__ float dppf(float x) {
    return __int_as_float(
        __builtin_amdgcn_update_dpp(0, __float_as_int(x), CTRL, RM, 0xF, true));
}
template <int CTRL>
__device__ __forceinline__ int dppi(int x) {
    return __builtin_amdgcn_update_dpp(0, x, CTRL, 0xF, 0xF, true);
}
__device__ __forceinline__ float bcast63(float x) {
    return __int_as_float(__builtin_amdgcn_readlane(__float_as_int(x), 63));
}
// full-wave sum of non-negative values, result broadcast
__device__ __forceinline__ float wsum(float x) {
    x += dppf<0x111>(x);          // row_shr:1
    x += dppf<0x112>(x);          // row_shr:2
    x += dppf<0x114>(x);          // row_shr:4
    x += dppf<0x118>(x);          // row_shr:8
    x += dppf<0x142, 0xA>(x);     // row_bcast:15 -> rows 1,3
    x += dppf<0x143, 0xC>(x);     // row_bcast:31 -> rows 2,3
    return bcast63(x);
}
__device__ __forceinline__ float shup1(float x) { return dppf<0x138>(x); } // lane i <- i-1, 0 into lane 0
__device__ __forceinline__ float shdn1(float x) { return dppf<0x130>(x); } // lane i <- i+1, 0 into lane 63
__device__ __forceinline__ float exp2i(int d) {  // 2^d, clamped to fp32-normal range
    d = d < -126 ? -126 : (d > 126 ? 126 : d);
    return __int_as_float((d + 127) << 23);
}

// ---- load one 8-row group of logits (dir wave-uniform) ----
__device__ __forceinline__ void load_group(const float2* __restrict__ rp2, float2* q,
                                           int dir, int g, int lane) {
#pragma unroll
    for (int j = 0; j < Gg; ++j) {
        int k = g * Gg + j;
        int t = dir ? (Tt - 1 - k) : k;
        q[j] = (lane < 48) ? rp2[(size_t)t * 48 + lane] : make_float2(-1e4f, -1e4f);
    }
}

// ---- softmax + gather one group into registers (verified arithmetic) ----
__device__ __forceinline__ void softmax_group(const float2* q, float* pl, float* pb,
                                              int idx_h, int bitsel) {
#pragma unroll
    for (int j = 0; j < Gg; ++j) {
        float ex = __builtin_amdgcn_exp2f(q[j].x * L2E);   // lanes>=48: 0
        float ey = __builtin_amdgcn_exp2f(q[j].y * L2E);
        float gb = __shfl(ey, 47, 64);      // class 95 (blank)
        float g0 = __shfl(ex, idx_h, 64);   // class 2*idx_h
        float g1 = __shfl(ey, idx_h, 64);   // class 2*idx_h+1
        float s  = wsum(ex + ey);
        float rZ = __builtin_amdgcn_rcpf(s);
        pl[j] = (bitsel ? g1 : g0) * rZ;
        pb[j] = gb * rZ;
    }
}

// ---- one 8-step DP group from an LDS slot (verified) ----
template <bool FWD>
__device__ __forceinline__ void dp_group(const float* __restrict__ pr, int lane,
                                         float allow2f, float& st_e, float& st_o,
                                         int& ls, float& f, float& a2f) {
    float plC[Gg], pbC[Gg];
#pragma unroll
    for (int j = 0; j < Gg; ++j) {
        plC[j] = pr[j * RSo + lane];   // 2-way bank alias (free)
        pbC[j] = pr[j * RSo + 49];     // uniform -> broadcast
    }
#pragma unroll
    for (int j = 0; j < Gg; ++j) {
        if (FWD) {
            float sh = shup1(st_o);
            float t0 = st_e + st_o;
            float ne = fmaf(f, sh, st_e) * pbC[j];
            float no = fmaf(a2f, sh, t0) * plC[j];
            st_e = ne; st_o = no;
        } else {
            float en = shdn1(st_e);
            float on = shdn1(st_o);
            float ne = (st_e + st_o) * pbC[j];
            float no = fmaf(a2f, on, fmaf(f, en, st_o)) * plC[j];
            st_e = ne; st_o = no;
        }
    }
    float m = fmaxf(st_e, st_o);
    bool z  = (m == 0.0f);
    int eb  = (__float_as_int(m) >> 23) & 0xFF;
    eb = eb > 253 ? 253 : eb;
    float r = z ? 1.0f : __int_as_float((254 - eb) << 23);
    st_e *= r; st_o *= r;
    ls += z ? 0 : (eb - 127);
#pragma unroll
    for (int it = 0; it < 8; ++it) {
        int lsn = FWD ? dppi<0x138>(ls) : dppi<0x130>(ls);
        ls = z ? lsn : ls;
    }
    int lsn2 = FWD ? dppi<0x138>(ls) : dppi<0x130>(ls);
    f   = exp2i(lsn2 - ls);
    a2f = allow2f * f;
}

// 8 waves/block: wv0 = fwd DP, wv1 = bwd DP, wv2-4 = fwd producers, wv5-7 = bwd
// producers. Producers fill a 12-slot LDS ring per direction with per-group ready
// flags; DP waves chase with s_sleep spins. No lockstep barriers in the main loop.
__global__ __launch_bounds__(512, 8) void ctc_fb(const int* __restrict__ labels,
                                                 const float* __restrict__ pred,
                                                 float* __restrict__ nll) {
    const int b    = blockIdx.x;
    const int lane = threadIdx.x & 63;
    const int wv   = threadIdx.x >> 6;
    const float2* rp2 = (const float2*)(pred + (size_t)b * Tt * Cc);

    __shared__ float plb[2 * RING * SLOT + 16];   // +16 pad for lane>49 tail reads
    __shared__ int   flg[2 * NG];
    __shared__ int   cons[2];
    __shared__ float sbe[64], sbo[64];
    __shared__ int   slsb[64];

    // zero ring (finite-junk guarantee for racy tail reads) + flags + counters
    for (int i = threadIdx.x; i < 2 * RING * SLOT + 16; i += 512) plb[i] = 0.0f;
    if (threadIdx.x < 2 * NG) flg[threadIdx.x] = 0;
    if (threadIdx.x < 2) cons[threadIdx.x] = 0;
    __syncthreads();

    // lane i holds label i (all waves)
    int v = (lane < Ll) ? labels[(size_t)b * Ll + lane] : -1;
    int present = (lane < Ll) && (v != -1);
    int labv = (v < 0) ? 0 : v;
    unsigned long long pm = __ballot(present);
    int len = __popcll(pm);
    int idx_h  = labv >> 1;
    int bitsel = labv & 1;
    int lab_p = __shfl(labv, (lane - 1) & 63, 64);
    int lab_n = __shfl(labv, (lane + 1) & 63, 64);

    if (wv >= 2) {
        // ---------------- producer ----------------
        const int dir = (wv >= 5) ? 1 : 0;
        const int q   = wv - (dir ? 5 : 2);       // 0..2, groups q, q+3, ..., q+21
        float2 qa[Gg], qb[Gg];
        load_group(rp2, qa, dir, q, lane);
        if (q + 3 < NG) load_group(rp2, qb, dir, q + 3, lane);
#pragma unroll
        for (int i = 0; i < 8; ++i) {
            const int g = q + 3 * i;
            float pl[Gg], pb[Gg];
            softmax_group((i & 1) ? qb : qa, pl, pb, idx_h, bitsel);
            if (i + 2 < 8) load_group(rp2, (i & 1) ? qb : qa, dir, q + 3 * (i + 2), lane);
            // ring slot free? need cons >= g-11
            if (g >= RING) {
                while (*(volatile int*)&cons[dir] < g - RING + 1)
                    __builtin_amdgcn_s_sleep(1);
            }
            float* dst = &plb[(dir * RING + (g % RING)) * SLOT];
#pragma unroll
            for (int j = 0; j < Gg; ++j)
                if (lane < RSo) dst[j * RSo + lane] = (lane == 49) ? pb[j] : pl[j];
            asm volatile("s_waitcnt lgkmcnt(0)" ::: "memory");   // data before flag
            if (lane == 0) *(volatile int*)&flg[dir * NG + g] = 1;
        }
    } else {
        // ---------------- DP consumer ----------------
        const int dir = wv;
        float st_e, st_o = 0.0f, f = 1.0f, a2f, allow2f;
        int   ls = 0;
        if (dir == 0) {
            allow2f = (lane >= 1 && labv != lab_p) ? 1.0f : 0.0f;
            st_e = (lane == 0) ? 1.0f : 0.0f;
        } else {
            allow2f = (labv != lab_n) ? 1.0f : 0.0f;
            st_e = (lane == len) ? 1.0f : 0.0f;
        }
        a2f = allow2f;
        for (int g = 0; g < NG; ++g) {
            while (!*(volatile int*)&flg[dir * NG + g]) __builtin_amdgcn_s_sleep(1);
            asm volatile("" ::: "memory");   // no LDS-read hoist above the spin
            const float* pr = &plb[(dir * RING + (g % RING)) * SLOT];
            if (dir == 0)
                dp_group<true>(pr, lane, allow2f, st_e, st_o, ls, f, a2f);
            else
                dp_group<false>(pr, lane, allow2f, st_e, st_o, ls, f, a2f);
            asm volatile("" ::: "memory");   // reads retired before slot release
            if (lane == 0) *(volatile int*)&cons[dir] = g + 1;
        }
        if (dir == 1) {
            sbe[lane]  = st_e;
            sbo[lane]  = st_o;
            slsb[lane] = ls;
        }
        if (dir == 0) {
            // stash fwd state for the post-barrier combine
            // (kept in registers; combine below runs on wv0)
        }
        // fall through to barrier with state live (wv0 path continues below)
        if (dir == 0) {
            __syncthreads();   // producers + wv1 arrive here too (see below)
            // transition half-step (no emission) to meet beta at t = 192
            float sh  = shup1(st_o);
            int   lsu = dppi<0x138>(ls);
            float fup = exp2i(lsu - ls);
            float Ae = fmaf(fup, sh, st_e);
            float Ao = fmaf(allow2f * fup, sh, st_e + st_o);
            float be = sbe[lane], bo = sbo[lane];
            float base = (float)(ls + slsb[lane]);
            float l1 = (Ae > 0.0f && be > 0.0f) ? __log2f(Ae) + __log2f(be) + base : LNEG;
            float l2 = (Ao > 0.0f && bo > 0.0f) ? __log2f(Ao) + __log2f(bo) + base : LNEG;
            float mm = fmaxf(l1, l2);
#pragma unroll
            for (int off = 32; off >= 1; off >>= 1) mm = fmaxf(mm, __shfl_xor(mm, off, 64));
            float ss = exp2f(l1 - mm) + exp2f(l2 - mm);
#pragma unroll
            for (int off = 32; off >= 1; off >>= 1) ss += __shfl_xor(ss, off, 64);
            if (lane == 0) {
                float ll = (mm + __log2f(ss)) * LN2;
                nll[b] = -ll;
            }
            return;
        }
    }
    __syncthreads();   // producers and wv1 match wv0's barrier
}

// ---- mean of 1024 per-example NLLs, fixed-order f64, single block ----
__global__ __launch_bounds__(256) void ctc_mean(const float* __restrict__ nll,
                                                float* __restrict__ out, float invB) {
    __shared__ double part[256];
    double s = 0.0;
#pragma unroll
    for (int i = 0; i < 4; ++i) s += (double)nll[threadIdx.x + 256 * i];
    part[threadIdx.x] = s;
    __syncthreads();
#pragma unroll
    for (int w = 128; w >= 1; w >>= 1) {
        if (threadIdx.x < w) part[threadIdx.x] += part[threadIdx.x + w];
        __syncthreads();
    }
    if (threadIdx.x == 0) out[0] = (float)(part[0] * (double)invB);
}

extern "C" void kernel_launch(void* const* d_in, const int* in_sizes, int n_in,
                              void* d_out, int out_size, void* d_ws, size_t ws_size,
                              hipStream_t stream) {
    const int*   labels = (const int*)d_in[0];
    const float* pred   = (const float*)d_in[1];
    float*       out    = (float*)d_out;
    float*       nll    = (float*)d_ws;    // 1024 floats = 4 KB

    const int B = in_sizes[0] / Ll;  // 1024

    hipLaunchKernelGGL(ctc_fb, dim3(B), dim3(512), 0, stream, labels, pred, nll);
    hipLaunchKernelGGL(ctc_mean, dim3(1), dim3(256), 0, stream, nll, out, 1.0f / (float)B);
}

// Round 9
// 220.013 us; speedup vs baseline: 1.0818x; 1.0818x over previous
//
#include <hip/hip_runtime.h>

constexpr int Tt = 384;   // timesteps
constexpr int Cc = 96;    // classes (blank = 95)
constexpr int Ll = 48;    // max label length
constexpr int Gg = 8;     // rows per group (= rescale period)
constexpr int NG = 24;    // groups per half (24*8 = 192)

#define L2E 1.4426950408889634f
#define LN2 0.6931471805599453f
#define LNEG (-3.0e38f)

// ---- DPP helpers (VALU pipe) ----
template <int CTRL, int RM = 0xF>
__device__ __forceinline__ float dppf(float x) {
    return __int_as_float(
        __builtin_amdgcn_update_dpp(0, __float_as_int(x), CTRL, RM, 0xF, true));
}
template <int CTRL>
__device__ __forceinline__ int dppi(int x) {
    return __builtin_amdgcn_update_dpp(0, x, CTRL, 0xF, 0xF, true);
}
__device__ __forceinline__ float bcast63(float x) {
    return __int_as_float(__builtin_amdgcn_readlane(__float_as_int(x), 63));
}
// full-wave sum of non-negative values, result broadcast
__device__ __forceinline__ float wsum(float x) {
    x += dppf<0x111>(x);          // row_shr:1
    x += dppf<0x112>(x);          // row_shr:2
    x += dppf<0x114>(x);          // row_shr:4
    x += dppf<0x118>(x);          // row_shr:8
    x += dppf<0x142, 0xA>(x);     // row_bcast:15 -> rows 1,3
    x += dppf<0x143, 0xC>(x);     // row_bcast:31 -> rows 2,3
    return bcast63(x);
}
__device__ __forceinline__ float shup1(float x) { return dppf<0x138>(x); } // lane i <- i-1, 0 into lane 0
__device__ __forceinline__ float shdn1(float x) { return dppf<0x130>(x); } // lane i <- i+1, 0 into lane 63
__device__ __forceinline__ float exp2i(int d) {  // 2^d, clamped to fp32-normal range
    d = d < -126 ? -126 : (d > 126 ? 126 : d);
    return __int_as_float((d + 127) << 23);
}

// ---- load one 8-row group of logits ----
template <bool FWD>
__device__ __forceinline__ void prod_load(const float2* __restrict__ rp2, float2* q,
                                          int g, int lane) {
#pragma unroll
    for (int j = 0; j < Gg; ++j) {
        int k = g * Gg + j;
        int t = FWD ? k : (Tt - 1 - k);
        q[j] = (lane < 48) ? rp2[(size_t)t * 48 + lane] : make_float2(-1e4f, -1e4f);
    }
}

// ---- gather UNNORMALIZED e-values + accumulate log2(Z) on a side-chain ----
// el[j] = e(label_lane), eb[j] = e(blank) with e = exp2(logit*L2E) (no normalization;
// the DP chain no longer waits on wsum/rcp). zacc += log2(Z_row) runs as independent
// ILP; Z factorization verified in R6 (log a_unnorm = log a + sum log Z; per-lane
// power-of-2 rescale is exact and Z is lane-common).
__device__ __forceinline__ void gather_group(const float2* q, float* el, float* eb,
                                             int idx_h, int bitsel, double& zacc) {
#pragma unroll
    for (int j = 0; j < Gg; ++j) {
        float ex = __builtin_amdgcn_exp2f(q[j].x * L2E);   // lanes>=48: 0
        float ey = __builtin_amdgcn_exp2f(q[j].y * L2E);
        float gb = __shfl(ey, 47, 64);      // class 95 (blank)
        float g0 = __shfl(ex, idx_h, 64);   // class 2*idx_h
        float g1 = __shfl(ey, idx_h, 64);   // class 2*idx_h+1
        el[j] = bitsel ? g1 : g0;
        eb[j] = gb;
        float s = wsum(ex + ey);            // independent of el/eb consumers
        zacc += (double)__log2f(s);         // wave-uniform (wsum broadcasts)
    }
}

// ---- one 8-step DP group on unnormalized emissions (verified R6 arithmetic) ----
template <bool FWD>
__device__ __forceinline__ void dp_group(const float* el, const float* eb,
                                         float allow2f, float& st_e, float& st_o,
                                         int& ls, float& f, float& a2f) {
#pragma unroll
    for (int j = 0; j < Gg; ++j) {
        if (FWD) {
            float sh = shup1(st_o);                      // alpha(2i-1), lane i-1 scale
            float t0 = st_e + st_o;
            float ne = fmaf(f, sh, st_e) * eb[j];
            float no = fmaf(a2f, sh, t0) * el[j];
            st_e = ne; st_o = no;
        } else {
            float en = shdn1(st_e);                      // beta(2i+2)
            float on = shdn1(st_o);                      // beta(2i+3)
            float ne = (st_e + st_o) * eb[j];
            float no = fmaf(a2f, on, fmaf(f, en, st_o)) * el[j];
            st_e = ne; st_o = no;
        }
    }
    // per-lane exact power-of-2 rescale (absorbs unnormalized dynamic range)
    float m = fmaxf(st_e, st_o);
    bool z  = (m == 0.0f);
    int eb2 = (__float_as_int(m) >> 23) & 0xFF;
    eb2 = eb2 > 253 ? 253 : eb2;
    float r = z ? 1.0f : __int_as_float((254 - eb2) << 23);   // 2^(127-eb2), exact
    st_e *= r; st_o *= r;
    ls += z ? 0 : (eb2 - 127);
    // exponent adoption for zero lanes (front moves <= 8 lanes/group)
#pragma unroll
    for (int it = 0; it < 8; ++it) {
        int lsn = FWD ? dppi<0x138>(ls) : dppi<0x130>(ls);
        ls = z ? lsn : ls;
    }
    int lsn2 = FWD ? dppi<0x138>(ls) : dppi<0x130>(ls);
    f   = exp2i(lsn2 - ls);
    a2f = allow2f * f;
}

// ---- self-contained half-problem: 24 groups, software-pipelined, no barriers ----
template <bool FWD>
__device__ __forceinline__ void run_half(const float2* __restrict__ rp2, int lane,
                                         int idx_h, int bitsel, float allow2f,
                                         float& st_e, float& st_o, int& ls,
                                         float& f, float& a2f, double& zacc) {
    float2 q0[Gg], q1[Gg];
    float elA[Gg], ebA[Gg], elB[Gg], ebB[Gg];
    prod_load<FWD>(rp2, q0, 0, lane);
    prod_load<FWD>(rp2, q1, 1, lane);
    gather_group(q0, elA, ebA, idx_h, bitsel, zacc);     // group 0
    for (int g2 = 0; g2 < NG / 2; ++g2) {                // 12 iterations, 2 groups each
        bool more = (g2 < NG / 2 - 1);
        if (more) prod_load<FWD>(rp2, q0, 2 * g2 + 2, lane);
        gather_group(q1, elB, ebB, idx_h, bitsel, zacc); // group 2*g2+1 (fills DP stalls)
        dp_group<FWD>(elA, ebA, allow2f, st_e, st_o, ls, f, a2f);   // group 2*g2
        if (more) prod_load<FWD>(rp2, q1, 2 * g2 + 3, lane);
        if (more) gather_group(q0, elA, ebA, idx_h, bitsel, zacc);  // group 2*g2+2
        dp_group<FWD>(elB, ebB, allow2f, st_e, st_o, ls, f, a2f);   // group 2*g2+1
    }
}

// 2 waves/block: wv0 = fwd half (t=0..191), wv1 = bwd half (t=383..192). No main-loop
// barriers; one barrier to combine at t=192. Per-example NLL -> ws[b] (no atomics).
__global__ __launch_bounds__(128) void ctc_fb(const int* __restrict__ labels,
                                              const float* __restrict__ pred,
                                              float* __restrict__ nll) {
    const int b    = blockIdx.x;
    const int lane = threadIdx.x & 63;
    const int wv   = threadIdx.x >> 6;
    const float2* rp2 = (const float2*)(pred + (size_t)b * Tt * Cc);

    __shared__ float  sbe[64], sbo[64];
    __shared__ int    slsb[64];
    __shared__ double szb;

    // lane i holds label i
    int v = (lane < Ll) ? labels[(size_t)b * Ll + lane] : -1;
    int present = (lane < Ll) && (v != -1);
    int labv = (v < 0) ? 0 : v;
    unsigned long long pm = __ballot(present);
    int len = __popcll(pm);
    int idx_h  = labv >> 1;
    int bitsel = labv & 1;
    int lab_p = __shfl(labv, (lane - 1) & 63, 64);
    int lab_n = __shfl(labv, (lane + 1) & 63, 64);

    float st_e, st_o = 0.0f, f = 1.0f, a2f, allow2f;
    int   ls = 0;
    double zacc = 0.0;

    if (wv == 0) {            // fwd DP: virtual pre-start state at lane 0
        allow2f = (lane >= 1 && labv != lab_p) ? 1.0f : 0.0f;
        st_e = (lane == 0) ? 1.0f : 0.0f;
        a2f = allow2f;
        run_half<true>(rp2, lane, idx_h, bitsel, allow2f, st_e, st_o, ls, f, a2f, zacc);
    } else {                  // bwd DP: virtual post-end state at lane == len
        allow2f = (labv != lab_n) ? 1.0f : 0.0f;
        st_e = (lane == len) ? 1.0f : 0.0f;
        a2f = allow2f;
        run_half<false>(rp2, lane, idx_h, bitsel, allow2f, st_e, st_o, ls, f, a2f, zacc);
        sbe[lane]  = st_e;
        sbo[lane]  = st_o;
        slsb[lane] = ls;
        if (lane == 0) szb = zacc;   // wave-uniform
    }
    __syncthreads();

    if (wv == 0) {
        // transition half-step (no emission) to meet beta at t = 192
        float sh  = shup1(st_o);
        int   lsu = dppi<0x138>(ls);
        float fup = exp2i(lsu - ls);
        float Ae = fmaf(fup, sh, st_e);
        float Ao = fmaf(allow2f * fup, sh, st_e + st_o);
        // combine in log2 domain with integer exponents restored
        float be = sbe[lane], bo = sbo[lane];
        float base = (float)(ls + slsb[lane]);
        float l1 = (Ae > 0.0f && be > 0.0f) ? __log2f(Ae) + __log2f(be) + base : LNEG;
        float l2 = (Ao > 0.0f && bo > 0.0f) ? __log2f(Ao) + __log2f(bo) + base : LNEG;
        float mm = fmaxf(l1, l2);
#pragma unroll
        for (int off = 32; off >= 1; off >>= 1) mm = fmaxf(mm, __shfl_xor(mm, off, 64));
        float ss = exp2f(l1 - mm) + exp2f(l2 - mm);
#pragma unroll
        for (int off = 32; off >= 1; off >>= 1) ss += __shfl_xor(ss, off, 64);
        if (lane == 0) {
            // subtract the factored-out log2(prod_t Z_t) over both halves
            double zt = zacc + szb;
            float ll = (mm + __log2f(ss) - (float)zt) * LN2;
            nll[b] = -ll;                 // plain store, no contended atomic
        }
    }
}

// ---- mean of 1024 per-example NLLs, fixed-order f64, single block ----
__global__ __launch_bounds__(256) void ctc_mean(const float* __restrict__ nll,
                                                float* __restrict__ out, float invB) {
    __shared__ double part[256];
    double s = 0.0;
#pragma unroll
    for (int i = 0; i < 4; ++i) s += (double)nll[threadIdx.x + 256 * i];
    part[threadIdx.x] = s;
    __syncthreads();
#pragma unroll
    for (int w = 128; w >= 1; w >>= 1) {
        if (threadIdx.x < w) part[threadIdx.x] += part[threadIdx.x + w];
        __syncthreads();
    }
    if (threadIdx.x == 0) out[0] = (float)(part[0] * (double)invB);
}

extern "C" void kernel_launch(void* const* d_in, const int* in_sizes, int n_in,
                              void* d_out, int out_size, void* d_ws, size_t ws_size,
                              hipStream_t stream) {
    const int*   labels = (const int*)d_in[0];
    const float* pred   = (const float*)d_in[1];
    float*       out    = (float*)d_out;
    float*       nll    = (float*)d_ws;    // 1024 floats = 4 KB

    const int B = in_sizes[0] / Ll;  // 1024

    hipLaunchKernelGGL(ctc_fb, dim3(B), dim3(128), 0, stream, labels, pred, nll);
    hipLaunchKernelGGL(ctc_mean, dim3(1), dim3(256), 0, stream, nll, out, 1.0f / (float)B);
}